// Round 7
// baseline (1558.425 us; speedup 1.0000x reference)
//
#include <hip/hip_runtime.h>

#define EPS 1e-5f

constexpr int Bb  = 128;     // batches
constexpr int Np  = 8192;    // points per batch
constexpr int C1  = 64, C2 = 128, C3 = 256;
constexpr int WAVES = 8;     // waves per block (512 threads)
constexpr int P   = 128;     // points per chunk = 8 waves x 16 rows
constexpr int CHUNKS = 8;
constexpr int PTS_PER_BLOCK = P * CHUNKS;          // 1024
constexpr int BLK_PER_BATCH = Np / PTS_PER_BLOCK;  // 8

typedef __attribute__((ext_vector_type(8))) short short8v;  // 8 bf16 = 4 VGPR
typedef __attribute__((ext_vector_type(4))) float f32x4;    // MFMA acc

__device__ __forceinline__ ushort f2bf(float f) {
  uint x = __float_as_uint(f);
  return (ushort)((x + 0x7fffu + ((x >> 16) & 1u)) >> 16);   // RNE
}

// ---------------------------------------------------------------------------
// prepW: pack W2 [64][128] and W3 [128][256] (f32) into bf16 B-fragments for
// v_mfma_f32_16x16x32_bf16.  Frag order: [tile][kk][lane][i] with
// k = kk*32 + (lane>>4)*8 + i,  n = tile*16 + (lane&15).
// ---------------------------------------------------------------------------
__global__ __launch_bounds__(256) void prepW(const float* __restrict__ W2,
                                             const float* __restrict__ W3,
                                             ushort* __restrict__ W2s,
                                             ushort* __restrict__ W3s) {
  const int idx = blockIdx.x * 256 + threadIdx.x;   // 0..40959
  if (idx < 8192) {
    const int i  = idx & 7;
    const int l  = (idx >> 3) & 63;
    const int kk = (idx >> 9) & 1;
    const int t  = idx >> 10;
    const int k  = kk * 32 + (l >> 4) * 8 + i;
    const int n  = t * 16 + (l & 15);
    W2s[idx] = f2bf(W2[k * C2 + n]);
  } else {
    const int j  = idx - 8192;                      // 0..32767
    const int i  = j & 7;
    const int l  = (j >> 3) & 63;
    const int kk = (j >> 9) & 3;
    const int nt = j >> 11;
    const int k  = kk * 32 + (l >> 4) * 8 + i;
    const int n  = nt * 16 + (l & 15);
    W3s[j] = f2bf(W3[k * C3 + n]);
  }
}

// ---------------------------------------------------------------------------
// Stage A — ZERO-BARRIER chunk loop (r6 was ~88% latency/convoy-stalled):
//  * Each wave owns 16 rows x FULL N for all 3 layers -> LN1/LN2/LN3 are all
//    in-wave shuffle reductions; h1/h2 are wave-private LDS regions; no
//    __syncthreads() inside the chunk loop at all.
//  * W2/W3 fragments AND all LN params staged to LDS once per block (the r6
//    global param loads in the loop were ~200-cyc critical-path stalls).
//  * Cost: W3 frags re-read per wave from LDS (~64KB/wave-chunk) -> LDS-BW
//    bound ~100-150us predicted, vs latency-bound 548us.
// s_par layout (floats): W1[3][64]@0, b1@192, g1@256, be1@320, b2@384,
//                        g2@512, be2@640, b3@768, g3@1024, be3@1280.
// ---------------------------------------------------------------------------
__global__ __launch_bounds__(512) void stageA(
    const float* __restrict__ pc,
    const float* __restrict__ W1, const float* __restrict__ b1,
    const float* __restrict__ g1, const float* __restrict__ be1,
    const ushort* __restrict__ W2s, const float* __restrict__ b2,
    const float* __restrict__ g2, const float* __restrict__ be2,
    const ushort* __restrict__ W3s, const float* __restrict__ b3,
    const float* __restrict__ g3, const float* __restrict__ be3,
    float* __restrict__ pooled)      // [B][C3], pre-zeroed, int-bits atomicMax
{
  __shared__ __align__(16) ushort s_w2[8192];          // 16KB W2 frags
  __shared__ __align__(16) ushort s_w3[32768];         // 64KB W3 frags
  __shared__ __align__(16) ushort s_h1[WAVES * 1024];  // 16KB per-wave 16x64
  __shared__ __align__(16) ushort s_h2[WAVES * 2048];  // 32KB per-wave 16x128
  __shared__ float s_par[1536];                        // 6KB LN/bias params

  const int tid  = threadIdx.x;          // 0..511

  // ---- one-time staging ----
  for (int i = tid; i < 1536; i += 512) {
    float v;
    if      (i <  192) v = W1 [i];
    else if (i <  256) v = b1 [i - 192];
    else if (i <  320) v = g1 [i - 256];
    else if (i <  384) v = be1[i - 320];
    else if (i <  512) v = b2 [i - 384];
    else if (i <  640) v = g2 [i - 512];
    else if (i <  768) v = be2[i - 640];
    else if (i < 1024) v = b3 [i - 768];
    else if (i < 1280) v = g3 [i - 1024];
    else               v = be3[i - 1280];
    s_par[i] = v;
  }
#pragma unroll
  for (int q = 0; q < 2; ++q)
    ((uint4*)s_w2)[q * 512 + tid] = ((const uint4*)W2s)[q * 512 + tid];
#pragma unroll
  for (int q = 0; q < 8; ++q)
    ((uint4*)s_w3)[q * 512 + tid] = ((const uint4*)W3s)[q * 512 + tid];
  __syncthreads();   // the ONLY barrier

  const int lane = tid & 63;
  const int w    = tid >> 6;
  const int lrow = lane & 15;            // A-row / C-D col index
  const int lgrp = lane >> 4;
  const int b    = blockIdx.x >> 3;      // / BLK_PER_BATCH
  const int base_pt = (blockIdx.x & (BLK_PER_BATCH - 1)) * PTS_PER_BLOCK;

  char* const h1b = (char*)(s_h1 + w * 1024);   // wave-private 16x64 bf16
  char* const h2b = (char*)(s_h2 + w * 2048);   // wave-private 16x128 bf16
  const int sw1 = (lrow & 7) << 4;

  float runmax[16];
#pragma unroll
  for (int t = 0; t < 16; ++t) runmax[t] = 0.f;

  for (int ch = 0; ch < CHUNKS; ++ch) {
    // ================= layer 1: 3 -> 64, fp32 VALU =================
    const float* xp = pc + (size_t)(b * Np + base_pt + ch * P + w * 16 + lrow) * 3;
    const float x0 = xp[0], x1 = xp[1], x2 = xp[2];
    float y[16];
#pragma unroll
    for (int j = 0; j < 16; ++j) {
      const int c = lgrp * 16 + j;
      y[j] = x0 * s_par[c] + x1 * s_par[64 + c] + x2 * s_par[128 + c] + s_par[192 + c];
    }
    float s1 = 0.f, q1 = 0.f;
#pragma unroll
    for (int j = 0; j < 16; ++j) { s1 += y[j]; q1 += y[j] * y[j]; }
    s1 += __shfl_xor(s1, 16, 64); q1 += __shfl_xor(q1, 16, 64);
    s1 += __shfl_xor(s1, 32, 64); q1 += __shfl_xor(q1, 32, 64);
    const float m1 = s1 * (1.f / 64.f);
    const float i1 = rsqrtf(q1 * (1.f / 64.f) - m1 * m1 + EPS);
    {
      uint pk[8];
#pragma unroll
      for (int j2 = 0; j2 < 8; ++j2) {
        const int c0 = lgrp * 16 + 2 * j2;
        const float h0 = fmaxf((y[2 * j2]     - m1) * i1 * s_par[256 + c0]     + s_par[320 + c0],     0.f);
        const float h1 = fmaxf((y[2 * j2 + 1] - m1) * i1 * s_par[256 + c0 + 1] + s_par[320 + c0 + 1], 0.f);
        pk[j2] = (uint)f2bf(h0) | ((uint)f2bf(h1) << 16);
      }
      const int base = lrow * 128 + lgrp * 32;   // bytes
      *(uint4*)(h1b + ((base     ) ^ sw1)) = make_uint4(pk[0], pk[1], pk[2], pk[3]);
      *(uint4*)(h1b + ((base + 16) ^ sw1)) = make_uint4(pk[4], pk[5], pk[6], pk[7]);
    }
    // same-wave write->read ordering via compiler lgkmcnt; no barrier.

    // ================= layer 2: 64 -> 128, MFMA (in-wave) =================
    short8v a2[2];
#pragma unroll
    for (int kk = 0; kk < 2; ++kk)
      a2[kk] = *(const short8v*)(h1b + ((lrow * 128 + (kk * 64 + lgrp * 16)) ^ sw1));
    {
      f32x4 acc2[8];
      float s2[4] = {0.f,0.f,0.f,0.f}, q2[4] = {0.f,0.f,0.f,0.f};
#pragma unroll
      for (int t = 0; t < 8; ++t) {
        acc2[t] = (f32x4){0.f, 0.f, 0.f, 0.f};
#pragma unroll
        for (int kk = 0; kk < 2; ++kk) {
          const short8v w2f = *(const short8v*)((const char*)s_w2 + (((t * 2 + kk) << 6) + lane) * 16);
          acc2[t] = __builtin_amdgcn_mfma_f32_16x16x32_bf16(a2[kk], w2f, acc2[t], 0, 0, 0);
        }
        const float bb = s_par[384 + t * 16 + lrow];
#pragma unroll
        for (int j = 0; j < 4; ++j) {
          const float v = acc2[t][j] + bb;
          acc2[t][j] = v;
          s2[j] += v; q2[j] += v * v;
        }
      }
#pragma unroll
      for (int m = 1; m < 16; m <<= 1)
#pragma unroll
        for (int j = 0; j < 4; ++j) {
          s2[j] += __shfl_xor(s2[j], m, 64);
          q2[j] += __shfl_xor(q2[j], m, 64);
        }
#pragma unroll
      for (int j = 0; j < 4; ++j) {
        const float m2 = s2[j] * (1.f / 128.f);
        const float i2 = rsqrtf(q2[j] * (1.f / 128.f) - m2 * m2 + EPS);
        const int row = lgrp * 4 + j;              // wave-local row
        const int swr = (row & 7) << 4;
#pragma unroll
        for (int t = 0; t < 8; ++t) {
          const int col = t * 16 + lrow;
          const float h = fmaxf((acc2[t][j] - m2) * i2 * s_par[512 + col] + s_par[640 + col], 0.f);
          *(ushort*)(h2b + row * 256 + ((t * 32 + lrow * 2) ^ swr)) = f2bf(h);
        }
      }
    }

    // ================= layer 3: 128 -> 256, MFMA (in-wave LN) ==============
    short8v a3[4];
#pragma unroll
    for (int kk = 0; kk < 4; ++kk)
      a3[kk] = *(const short8v*)(h2b + ((lrow * 256) + ((kk * 64 + lgrp * 16) ^ ((lrow & 7) << 4))));

    f32x4 acc3[16];
    float sj[4] = {0.f,0.f,0.f,0.f}, qj[4] = {0.f,0.f,0.f,0.f};
#pragma unroll
    for (int t = 0; t < 16; ++t) {
      acc3[t] = (f32x4){0.f, 0.f, 0.f, 0.f};
#pragma unroll
      for (int kk = 0; kk < 4; ++kk) {
        const short8v w3f = *(const short8v*)((const char*)s_w3 + (((t * 4 + kk) << 6) + lane) * 16);
        acc3[t] = __builtin_amdgcn_mfma_f32_16x16x32_bf16(a3[kk], w3f, acc3[t], 0, 0, 0);
      }
      const float bb = s_par[768 + t * 16 + lrow];
#pragma unroll
      for (int j = 0; j < 4; ++j) {
        const float v = acc3[t][j] + bb;
        acc3[t][j] = v;
        sj[j] += v; qj[j] += v * v;
      }
    }
#pragma unroll
    for (int m = 1; m < 16; m <<= 1)
#pragma unroll
      for (int j = 0; j < 4; ++j) {
        sj[j] += __shfl_xor(sj[j], m, 64);
        qj[j] += __shfl_xor(qj[j], m, 64);
      }
    float mean3[4], inv3[4];
#pragma unroll
    for (int j = 0; j < 4; ++j) {
      mean3[j] = sj[j] * (1.f / 256.f);
      inv3[j]  = rsqrtf(qj[j] * (1.f / 256.f) - mean3[j] * mean3[j] + EPS);
    }
#pragma unroll
    for (int t = 0; t < 16; ++t) {
      const int col = t * 16 + lrow;
      const float gg = s_par[1024 + col], ee = s_par[1280 + col];
      float mx = runmax[t];
#pragma unroll
      for (int j = 0; j < 4; ++j) {
        const float h = fmaxf((acc3[t][j] - mean3[j]) * inv3[j] * gg + ee, 0.f);
        mx = fmaxf(mx, h);
      }
      runmax[t] = mx;
    }
  }

  // ---- col max across the 4 lgrp groups, then global atomic ----
#pragma unroll
  for (int t = 0; t < 16; ++t) {
    float v = runmax[t];
    v = fmaxf(v, __shfl_xor(v, 16, 64));
    v = fmaxf(v, __shfl_xor(v, 32, 64));
    if (lane < 16)
      atomicMax((int*)&pooled[b * C3 + t * 16 + lane], __float_as_int(v));
  }
}

// ---------------------------------------------------------------------------
// Stage B: pooled -> LN(pooled@Wp+bp) -> film = pc@Wf+bf -> out = s*img + b
// ---------------------------------------------------------------------------
__global__ __launch_bounds__(256) void stageB(
    const float* __restrict__ pooled,  // [B][256]
    const float* __restrict__ img,     // [B][512]
    const float* __restrict__ Wp, const float* __restrict__ bp,
    const float* __restrict__ gp, const float* __restrict__ bep,
    const float* __restrict__ Wf, const float* __restrict__ bf,
    float* __restrict__ out)           // [B][512]
{
  __shared__ float s_pool[C3];
  __shared__ float s_pc[C3];
  __shared__ float s_red[8];

  const int t = threadIdx.x, b = blockIdx.x;
  const int lane = t & 63, w = t >> 6;

  s_pool[t] = pooled[b * C3 + t];
  __syncthreads();

  float y = bp[t];
  for (int k = 0; k < C3; ++k) y += s_pool[k] * Wp[k * C3 + t];

  float s = y, q = y * y;
  for (int m = 1; m < 64; m <<= 1) { s += __shfl_xor(s, m, 64); q += __shfl_xor(q, m, 64); }
  if (lane == 0) { s_red[w * 2] = s; s_red[w * 2 + 1] = q; }
  __syncthreads();
  s = s_red[0] + s_red[2] + s_red[4] + s_red[6];
  q = s_red[1] + s_red[3] + s_red[5] + s_red[7];
  const float mean = s * (1.f / 256.f);
  const float var  = q * (1.f / 256.f) - mean * mean;
  const float inv  = rsqrtf(var + EPS);
  s_pc[t] = (y - mean) * inv * gp[t] + bep[t];
  __syncthreads();

  float f0 = bf[t], f1 = bf[256 + t], f2 = bf[512 + t], f3 = bf[768 + t];
  for (int k = 0; k < C3; ++k) {
    const float pv = s_pc[k];
    f0 += pv * Wf[k * 1024 + t];
    f1 += pv * Wf[k * 1024 + 256 + t];
    f2 += pv * Wf[k * 1024 + 512 + t];
    f3 += pv * Wf[k * 1024 + 768 + t];
  }
  out[b * 512 + t]       = f0 * img[b * 512 + t]       + f2;
  out[b * 512 + 256 + t] = f1 * img[b * 512 + 256 + t] + f3;
}

extern "C" void kernel_launch(void* const* d_in, const int* in_sizes, int n_in,
                              void* d_out, int out_size, void* d_ws, size_t ws_size,
                              hipStream_t stream) {
  const float* pc  = (const float*)d_in[0];
  const float* img = (const float*)d_in[1];
  const float* W1  = (const float*)d_in[2];
  const float* b1  = (const float*)d_in[3];
  const float* g1  = (const float*)d_in[4];
  const float* be1 = (const float*)d_in[5];
  const float* W2  = (const float*)d_in[6];
  const float* b2  = (const float*)d_in[7];
  const float* g2  = (const float*)d_in[8];
  const float* be2 = (const float*)d_in[9];
  const float* W3  = (const float*)d_in[10];
  const float* b3  = (const float*)d_in[11];
  const float* g3  = (const float*)d_in[12];
  const float* be3 = (const float*)d_in[13];
  const float* Wp  = (const float*)d_in[14];
  const float* bp  = (const float*)d_in[15];
  const float* gp  = (const float*)d_in[16];
  const float* bep = (const float*)d_in[17];
  const float* Wf  = (const float*)d_in[18];
  const float* bf  = (const float*)d_in[19];

  float*  pooled = (float*)d_ws;                                   // 128 KB
  ushort* W2s = (ushort*)((char*)d_ws + Bb * C3 * sizeof(float));  // 16 KB
  ushort* W3s = W2s + 8192;                                        // 64 KB

  hipMemsetAsync(pooled, 0, Bb * C3 * sizeof(float), stream);
  prepW<<<160, 256, 0, stream>>>(W2, W3, W2s, W3s);
  stageA<<<Bb * BLK_PER_BATCH, 512, 0, stream>>>(
      pc, W1, b1, g1, be1, W2s, b2, g2, be2, W3s, b3, g3, be3, pooled);
  stageB<<<Bb, 256, 0, stream>>>(pooled, img, Wp, bp, gp, bep, Wf, bf,
                                 (float*)d_out);
}

// Round 8
// 457.652 us; speedup vs baseline: 3.4053x; 3.4053x over previous
//
#include <hip/hip_runtime.h>

#define EPS 1e-5f

constexpr int Bb  = 128;     // batches
constexpr int Np  = 8192;    // points per batch
constexpr int C1  = 64, C2 = 128, C3 = 256;
constexpr int P   = 64;      // points per chunk (one 16-row M-tile per wave)
constexpr int CHUNKS = 4;    // chunks per block
constexpr int PTS_PER_BLOCK = P * CHUNKS;          // 256
constexpr int BLK_PER_BATCH = Np / PTS_PER_BLOCK;  // 32

typedef __attribute__((ext_vector_type(8))) short short8v;  // 8 bf16 = 4 VGPR
typedef __attribute__((ext_vector_type(4))) float f32x4;    // MFMA acc

__device__ __forceinline__ ushort f2bf(float f) {
  uint x = __float_as_uint(f);
  return (ushort)((x + 0x7fffu + ((x >> 16) & 1u)) >> 16);   // RNE
}

// ---------------------------------------------------------------------------
// prepW: pack W2 [64][128] and W3 [128][256] (f32) into bf16 B-fragments for
// v_mfma_f32_16x16x32_bf16.  Frag order: [tile][kk][lane][i] with
// k = kk*32 + (lane>>4)*8 + i,  n = tile*16 + (lane&15).
// ---------------------------------------------------------------------------
__global__ __launch_bounds__(256) void prepW(const float* __restrict__ W2,
                                             const float* __restrict__ W3,
                                             ushort* __restrict__ W2s,
                                             ushort* __restrict__ W3s) {
  const int idx = blockIdx.x * 256 + threadIdx.x;   // 0..40959
  if (idx < 8192) {
    const int i  = idx & 7;
    const int l  = (idx >> 3) & 63;
    const int kk = (idx >> 9) & 1;
    const int t  = idx >> 10;
    const int k  = kk * 32 + (l >> 4) * 8 + i;
    const int n  = t * 16 + (l & 15);
    W2s[idx] = f2bf(W2[k * C2 + n]);
  } else {
    const int j  = idx - 8192;                      // 0..32767
    const int i  = j & 7;
    const int l  = (j >> 3) & 63;
    const int kk = (j >> 9) & 3;
    const int nt = j >> 11;
    const int k  = kk * 32 + (l >> 4) * 8 + i;
    const int n  = nt * 16 + (l & 15);
    W3s[j] = f2bf(W3[k * C3 + n]);
  }
}

// ---------------------------------------------------------------------------
// Stage A = r6 structure (548us, 184 VGPR, no spill) + latency fixes:
//  * ALL LN/bias params + W1 staged to s_par (6KB LDS) once per block —
//    r6 had ~40 global param loads per chunk on the barrier-convoy path.
//  * W2 fragments staged to LDS once (16KB) instead of per-chunk L2 reads.
//  * pc for chunk ch+1 prefetched into regs ~4 barriers before use.
//  * W3 frags stay register-resident (64 VGPR); two-pass L3 (recompute)
//    keeps demand ~128-190 — do NOT add occupancy hints (r4/r5/r7 lesson:
//    hints or 512-thread blocks pin the allocator to 128 and it spills).
// LDS ~49KB -> 3 blocks/CU.
// s_par layout (floats): W1[3][64]@0, b1@192, g1@256, be1@320, b2@384,
//                        g2@512, be2@640, b3@768, g3@1024, be3@1280.
// ---------------------------------------------------------------------------
__global__ __launch_bounds__(256) void stageA(
    const float* __restrict__ pc,
    const float* __restrict__ W1, const float* __restrict__ b1,
    const float* __restrict__ g1, const float* __restrict__ be1,
    const ushort* __restrict__ W2s, const float* __restrict__ b2,
    const float* __restrict__ g2, const float* __restrict__ be2,
    const ushort* __restrict__ W3s, const float* __restrict__ b3,
    const float* __restrict__ g3, const float* __restrict__ be3,
    float* __restrict__ pooled)      // [B][C3], pre-zeroed, int-bits atomicMax
{
  __shared__ __align__(16) ushort s_h1[4 * 16 * 64];  // 8KB, per-wave [16][64]
  __shared__ __align__(16) ushort s_h2[64 * 128];     // 16KB, [64][128]
  __shared__ __align__(16) ushort s_w2[8192];         // 16KB, W2 frags
  __shared__ float  s_par[1536];                      // 6KB params
  __shared__ float  s_red[4][64][2];                  // 2KB LN3 partials
  __shared__ float2 s_mi[64];                         // 512B (mean, inv)

  const int tid  = threadIdx.x;
  const int lane = tid & 63;
  const int w    = tid >> 6;
  const int lrow = lane & 15;        // A-row / C-D col index
  const int lgrp = lane >> 4;
  const int b    = blockIdx.x >> 5;                  // /32
  const int base_pt = (blockIdx.x & 31) * PTS_PER_BLOCK;

  // ---- one-time staging: params + W2 frags ----
  for (int i = tid; i < 1536; i += 256) {
    float v;
    if      (i <  192) v = W1 [i];
    else if (i <  256) v = b1 [i - 192];
    else if (i <  320) v = g1 [i - 256];
    else if (i <  384) v = be1[i - 320];
    else if (i <  512) v = b2 [i - 384];
    else if (i <  640) v = g2 [i - 512];
    else if (i <  768) v = be2[i - 640];
    else if (i < 1024) v = b3 [i - 768];
    else if (i < 1280) v = g3 [i - 1024];
    else               v = be3[i - 1280];
    s_par[i] = v;
  }
#pragma unroll
  for (int q = 0; q < 4; ++q)
    ((uint4*)s_w2)[q * 256 + tid] = ((const uint4*)W2s)[q * 256 + tid];

  // ---- persistent: W3 B-frags (wave's 4 N-tiles) = 64 VGPR ----
  short8v w3f[4][4];                  // [t][kk]
#pragma unroll
  for (int t = 0; t < 4; ++t)
#pragma unroll
    for (int kk = 0; kk < 4; ++kk)
      w3f[t][kk] = *(const short8v*)(W3s + (size_t)(((w * 4 + t) * 4 + kk) * 64 + lane) * 8);

  float runmax[4] = {0.f, 0.f, 0.f, 0.f};

  char* const h1b = (char*)s_h1 + w * 2048;   // wave-private 16x64 bf16 region
  const int sw1 = (lrow & 7) << 4;

  __syncthreads();   // staging visible

  // ---- prefetch chunk 0's point ----
  {
  }
  const float* xp0 = pc + (size_t)(b * Np + base_pt + w * 16 + lrow) * 3;
  float x0 = xp0[0], x1 = xp0[1], x2 = xp0[2];

  for (int ch = 0; ch < CHUNKS; ++ch) {
    // ================= layer 1: 3 -> 64, fp32 VALU =================
    float y[16];
#pragma unroll
    for (int j = 0; j < 16; ++j) {
      const int c = lgrp * 16 + j;
      y[j] = x0 * s_par[c] + x1 * s_par[64 + c] + x2 * s_par[128 + c] + s_par[192 + c];
    }
    // ---- issue next chunk's pc load NOW (consumed 4 barriers later) ----
    {
      const int chn = (ch + 1 < CHUNKS) ? ch + 1 : ch;
      const float* xpn = pc + (size_t)(b * Np + base_pt + chn * P + w * 16 + lrow) * 3;
      x0 = xpn[0]; x1 = xpn[1]; x2 = xpn[2];
    }
    float s1 = 0.f, q1 = 0.f;
#pragma unroll
    for (int j = 0; j < 16; ++j) { s1 += y[j]; q1 += y[j] * y[j]; }
    s1 += __shfl_xor(s1, 16, 64); q1 += __shfl_xor(q1, 16, 64);
    s1 += __shfl_xor(s1, 32, 64); q1 += __shfl_xor(q1, 32, 64);
    const float m1 = s1 * (1.f / 64.f);
    const float i1 = rsqrtf(q1 * (1.f / 64.f) - m1 * m1 + EPS);
    {
      uint pk[8];
#pragma unroll
      for (int j2 = 0; j2 < 8; ++j2) {
        const int c0 = lgrp * 16 + 2 * j2;
        const float h0 = fmaxf((y[2 * j2]     - m1) * i1 * s_par[256 + c0]     + s_par[320 + c0],     0.f);
        const float h1 = fmaxf((y[2 * j2 + 1] - m1) * i1 * s_par[256 + c0 + 1] + s_par[320 + c0 + 1], 0.f);
        pk[j2] = (uint)f2bf(h0) | ((uint)f2bf(h1) << 16);
      }
      const int base = lrow * 128 + lgrp * 32;   // bytes
      *(uint4*)(h1b + ((base     ) ^ sw1)) = make_uint4(pk[0], pk[1], pk[2], pk[3]);
      *(uint4*)(h1b + ((base + 16) ^ sw1)) = make_uint4(pk[4], pk[5], pk[6], pk[7]);
    }
    // wave-private region: compiler-inserted lgkmcnt orders write->read.

    // ================= layer 2: 64 -> 128, MFMA =================
    short8v a2[2];
#pragma unroll
    for (int kk = 0; kk < 2; ++kk)
      a2[kk] = *(const short8v*)(h1b + ((lrow * 128 + (kk * 64 + lgrp * 16)) ^ sw1));
    {
      f32x4 acc2[8];
      float s2[4] = {0.f,0.f,0.f,0.f}, q2[4] = {0.f,0.f,0.f,0.f};
#pragma unroll
      for (int t = 0; t < 8; ++t) {
        acc2[t] = (f32x4){0.f, 0.f, 0.f, 0.f};
#pragma unroll
        for (int kk = 0; kk < 2; ++kk) {
          const short8v w2f = *(const short8v*)((const char*)s_w2 + (((t * 2 + kk) << 6) + lane) * 16);
          acc2[t] = __builtin_amdgcn_mfma_f32_16x16x32_bf16(a2[kk], w2f, acc2[t], 0, 0, 0);
        }
        const float bb = s_par[384 + t * 16 + lrow];
#pragma unroll
        for (int j = 0; j < 4; ++j) {
          const float v = acc2[t][j] + bb;
          acc2[t][j] = v;
          s2[j] += v; q2[j] += v * v;
        }
      }
#pragma unroll
      for (int m = 1; m < 16; m <<= 1)
#pragma unroll
        for (int j = 0; j < 4; ++j) {
          s2[j] += __shfl_xor(s2[j], m, 64);
          q2[j] += __shfl_xor(q2[j], m, 64);
        }
#pragma unroll
      for (int j = 0; j < 4; ++j) {
        const float m2 = s2[j] * (1.f / 128.f);
        const float i2 = rsqrtf(q2[j] * (1.f / 128.f) - m2 * m2 + EPS);
        const int row = w * 16 + lgrp * 4 + j;
        const int swr = (row & 7) << 4;
#pragma unroll
        for (int t = 0; t < 8; ++t) {
          const int col = t * 16 + lrow;
          const float h = fmaxf((acc2[t][j] - m2) * i2 * s_par[512 + col] + s_par[640 + col], 0.f);
          *(ushort*)((char*)s_h2 + row * 256 + ((t * 32 + lrow * 2) ^ swr)) = f2bf(h);
        }
      }
    }
    __syncthreads();   // B1: h2 visible to all waves

    // ====== layer 3 pass 1: MFMA for LN stats only (transient acc) ======
#pragma unroll
    for (int g = 0; g < 4; ++g) {
      short8v a3[4];
      const int row = g * 16 + lrow;
      const int rb  = row * 256;
      const int swr = (row & 7) << 4;
#pragma unroll
      for (int kk = 0; kk < 4; ++kk)
        a3[kk] = *(const short8v*)((const char*)s_h2 + rb + ((kk * 64 + lgrp * 16) ^ swr));

      float sg[4] = {0.f,0.f,0.f,0.f}, qg[4] = {0.f,0.f,0.f,0.f};
#pragma unroll
      for (int t = 0; t < 4; ++t) {
        f32x4 acc = (f32x4){0.f, 0.f, 0.f, 0.f};
#pragma unroll
        for (int kk = 0; kk < 4; ++kk)
          acc = __builtin_amdgcn_mfma_f32_16x16x32_bf16(a3[kk], w3f[t][kk], acc, 0, 0, 0);
        const float bb = s_par[768 + w * 64 + t * 16 + lrow];
#pragma unroll
        for (int j = 0; j < 4; ++j) {
          const float v = acc[j] + bb;
          sg[j] += v; qg[j] += v * v;
        }
      }
#pragma unroll
      for (int m = 1; m < 16; m <<= 1)
#pragma unroll
        for (int j = 0; j < 4; ++j) {
          sg[j] += __shfl_xor(sg[j], m, 64);
          qg[j] += __shfl_xor(qg[j], m, 64);
        }
      if (lrow == 0) {
#pragma unroll
        for (int j = 0; j < 4; ++j) {
          const int row2 = g * 16 + lgrp * 4 + j;
          s_red[w][row2][0] = sg[j];
          s_red[w][row2][1] = qg[j];
        }
      }
    }
    __syncthreads();   // B2
    if (tid < 64) {
      const float ss = s_red[0][tid][0] + s_red[1][tid][0] + s_red[2][tid][0] + s_red[3][tid][0];
      const float qq = s_red[0][tid][1] + s_red[1][tid][1] + s_red[2][tid][1] + s_red[3][tid][1];
      const float mean = ss * (1.f / 256.f);
      s_mi[tid] = make_float2(mean, rsqrtf(qq * (1.f / 256.f) - mean * mean + EPS));
    }
    __syncthreads();   // B3

    // ====== layer 3 pass 2: recompute MFMA, normalize, running max ======
#pragma unroll
    for (int g = 0; g < 4; ++g) {
      short8v a3[4];
      const int row = g * 16 + lrow;
      const int rb  = row * 256;
      const int swr = (row & 7) << 4;
#pragma unroll
      for (int kk = 0; kk < 4; ++kk)
        a3[kk] = *(const short8v*)((const char*)s_h2 + rb + ((kk * 64 + lgrp * 16) ^ swr));

#pragma unroll
      for (int t = 0; t < 4; ++t) {
        f32x4 acc = (f32x4){0.f, 0.f, 0.f, 0.f};
#pragma unroll
        for (int kk = 0; kk < 4; ++kk)
          acc = __builtin_amdgcn_mfma_f32_16x16x32_bf16(a3[kk], w3f[t][kk], acc, 0, 0, 0);
        const int col = w * 64 + t * 16 + lrow;
        const float bb = s_par[768 + col], gg = s_par[1024 + col], ee = s_par[1280 + col];
        float mx = runmax[t];
#pragma unroll
        for (int j = 0; j < 4; ++j) {
          const float2 mi = s_mi[g * 16 + lgrp * 4 + j];
          const float h = fmaxf((acc[j] + bb - mi.x) * mi.y * gg + ee, 0.f);
          mx = fmaxf(mx, h);
        }
        runmax[t] = mx;
      }
    }
    __syncthreads();   // B4: protect h2/s_red/s_mi for next chunk
  }

  // ---- col max across lanes sharing lrow, then global atomic ----
#pragma unroll
  for (int t = 0; t < 4; ++t) {
    float v = runmax[t];
    v = fmaxf(v, __shfl_xor(v, 16, 64));
    v = fmaxf(v, __shfl_xor(v, 32, 64));
    if (lane < 16)
      atomicMax((int*)&pooled[b * C3 + w * 64 + t * 16 + lane], __float_as_int(v));
  }
}

// ---------------------------------------------------------------------------
// Stage B: pooled -> LN(pooled@Wp+bp) -> film = pc@Wf+bf -> out = s*img + b
// ---------------------------------------------------------------------------
__global__ __launch_bounds__(256) void stageB(
    const float* __restrict__ pooled,  // [B][256]
    const float* __restrict__ img,     // [B][512]
    const float* __restrict__ Wp, const float* __restrict__ bp,
    const float* __restrict__ gp, const float* __restrict__ bep,
    const float* __restrict__ Wf, const float* __restrict__ bf,
    float* __restrict__ out)           // [B][512]
{
  __shared__ float s_pool[C3];
  __shared__ float s_pc[C3];
  __shared__ float s_red[8];

  const int t = threadIdx.x, b = blockIdx.x;
  const int lane = t & 63, w = t >> 6;

  s_pool[t] = pooled[b * C3 + t];
  __syncthreads();

  float y = bp[t];
  for (int k = 0; k < C3; ++k) y += s_pool[k] * Wp[k * C3 + t];

  float s = y, q = y * y;
  for (int m = 1; m < 64; m <<= 1) { s += __shfl_xor(s, m, 64); q += __shfl_xor(q, m, 64); }
  if (lane == 0) { s_red[w * 2] = s; s_red[w * 2 + 1] = q; }
  __syncthreads();
  s = s_red[0] + s_red[2] + s_red[4] + s_red[6];
  q = s_red[1] + s_red[3] + s_red[5] + s_red[7];
  const float mean = s * (1.f / 256.f);
  const float var  = q * (1.f / 256.f) - mean * mean;
  const float inv  = rsqrtf(var + EPS);
  s_pc[t] = (y - mean) * inv * gp[t] + bep[t];
  __syncthreads();

  float f0 = bf[t], f1 = bf[256 + t], f2 = bf[512 + t], f3 = bf[768 + t];
  for (int k = 0; k < C3; ++k) {
    const float pv = s_pc[k];
    f0 += pv * Wf[k * 1024 + t];
    f1 += pv * Wf[k * 1024 + 256 + t];
    f2 += pv * Wf[k * 1024 + 512 + t];
    f3 += pv * Wf[k * 1024 + 768 + t];
  }
  out[b * 512 + t]       = f0 * img[b * 512 + t]       + f2;
  out[b * 512 + 256 + t] = f1 * img[b * 512 + 256 + t] + f3;
}

extern "C" void kernel_launch(void* const* d_in, const int* in_sizes, int n_in,
                              void* d_out, int out_size, void* d_ws, size_t ws_size,
                              hipStream_t stream) {
  const float* pc  = (const float*)d_in[0];
  const float* img = (const float*)d_in[1];
  const float* W1  = (const float*)d_in[2];
  const float* b1  = (const float*)d_in[3];
  const float* g1  = (const float*)d_in[4];
  const float* be1 = (const float*)d_in[5];
  const float* W2  = (const float*)d_in[6];
  const float* b2  = (const float*)d_in[7];
  const float* g2  = (const float*)d_in[8];
  const float* be2 = (const float*)d_in[9];
  const float* W3  = (const float*)d_in[10];
  const float* b3  = (const float*)d_in[11];
  const float* g3  = (const float*)d_in[12];
  const float* be3 = (const float*)d_in[13];
  const float* Wp  = (const float*)d_in[14];
  const float* bp  = (const float*)d_in[15];
  const float* gp  = (const float*)d_in[16];
  const float* bep = (const float*)d_in[17];
  const float* Wf  = (const float*)d_in[18];
  const float* bf  = (const float*)d_in[19];

  float*  pooled = (float*)d_ws;                                   // 128 KB
  ushort* W2s = (ushort*)((char*)d_ws + Bb * C3 * sizeof(float));  // 16 KB
  ushort* W3s = W2s + 8192;                                        // 64 KB

  hipMemsetAsync(pooled, 0, Bb * C3 * sizeof(float), stream);
  prepW<<<160, 256, 0, stream>>>(W2, W3, W2s, W3s);
  stageA<<<Bb * BLK_PER_BATCH, 256, 0, stream>>>(
      pc, W1, b1, g1, be1, W2s, b2, g2, be2, W3s, b3, g3, be3, pooled);
  stageB<<<Bb, 256, 0, stream>>>(pooled, img, Wp, bp, gp, bep, Wf, bf,
                                 (float*)d_out);
}